// Round 3
// baseline (935.307 us; speedup 1.0000x reference)
//
#include <hip/hip_runtime.h>
#include <hip/hip_bf16.h>

// Problem constants (fixed by setup_inputs)
constexpr int NROWS = 100000;
constexpr int K     = 512;
constexpr int C     = 64;
constexpr int E     = 3200000;

// Binned-scatter parameters
constexpr int SHIFT = 13;                              // bucket = pos >> SHIFT (8192 positions/bucket = 64KB of pack)
constexpr int NB    = (E + (1 << SHIFT) - 1) >> SHIFT; // 391 buckets
constexpr int CHUNK = 4096;                            // edges per bin_scatter block

// ---------------------------------------------------------------------------
// GEMM: h[N,64] = x[N,512] @ w[512,64], fp32 vector ALU.
// Tile 128 rows x 64 cols, KC=64, 8x4 register blocking per thread.
// ---------------------------------------------------------------------------
__global__ __launch_bounds__(256) void gemm64(const float* __restrict__ x,
                                              const float* __restrict__ w,
                                              float* __restrict__ h) {
  __shared__ float xs[128][65];   // +1 pad: broadcast reads conflict-free
  __shared__ float ws[64][64];
  const int t    = threadIdx.x;
  const int cg   = (t & 15) * 4;   // col base: 0..60
  const int rg   = (t >> 4) * 8;   // row base: 0..120
  const int row0 = blockIdx.x * 128;

  float acc[8][4] = {};

  for (int k0 = 0; k0 < K; k0 += 64) {
    {
      const float4* wg  = (const float4*)(w + (size_t)k0 * C);
      float4*       wsv = (float4*)&ws[0][0];
#pragma unroll
      for (int i = 0; i < 4; ++i) wsv[t + 256 * i] = wg[t + 256 * i];
    }
#pragma unroll
    for (int i = 0; i < 8; ++i) {
      int idx = t + 256 * i;          // 0..2047
      int r   = idx >> 4;             // 0..127
      int kk  = (idx & 15) * 4;       // 0..60
      int gr  = row0 + r;
      if (gr >= NROWS) gr = NROWS - 1;   // clamp: OOB-safe, result discarded
      float4 v = *(const float4*)(x + (size_t)gr * K + k0 + kk);
      xs[r][kk]     = v.x;
      xs[r][kk + 1] = v.y;
      xs[r][kk + 2] = v.z;
      xs[r][kk + 3] = v.w;
    }
    __syncthreads();

#pragma unroll 8
    for (int kk = 0; kk < 64; ++kk) {
      float4 wv = *(const float4*)&ws[kk][cg];
      float xr[8];
#pragma unroll
      for (int i = 0; i < 8; ++i) xr[i] = xs[rg + i][kk];
#pragma unroll
      for (int i = 0; i < 8; ++i) {
        acc[i][0] += xr[i] * wv.x;
        acc[i][1] += xr[i] * wv.y;
        acc[i][2] += xr[i] * wv.z;
        acc[i][3] += xr[i] * wv.w;
      }
    }
    __syncthreads();
  }

#pragma unroll
  for (int i = 0; i < 8; ++i) {
    int gr = row0 + rg + i;
    if (gr < NROWS) {
      float4 v = {acc[i][0], acc[i][1], acc[i][2], acc[i][3]};
      *(float4*)(h + (size_t)gr * C + cg) = v;
    }
  }
}

// ---------------------------------------------------------------------------
// CSR build v2 (unsharded): histogram -> scan -> two-pass BINNED scatter.
//
// Single-pass scatter had 7.5x write amplification (193 MB for 25.6 MB
// payload): random 8B stores -> one 64B line writeback each. Fix: counting
// scatter through a bucket-grouped intermediate. Pass A groups records by
// pos>>13 in LDS and writes contiguous per-bucket runs (line-filling).
// Pass B reads each bucket's contiguous records and scatters within a 64KB
// pack window that stays L2-resident until fully dirty.
//
// BUGFIX vs prev round: bin_scatter phase 3 must loop t..NB stride 256
// (NB=391 > blockDim=256). The single-pass version left gbase[256..390]
// uninitialized -> wild stores -> HSA abort.
// ---------------------------------------------------------------------------
__global__ __launch_bounds__(256) void hist_kernel(const int* __restrict__ row,
                                                   int* __restrict__ deg) {
  int e = blockIdx.x * 256 + threadIdx.x;
  if (e < E) {
    int r = __builtin_nontemporal_load(row + e);   // stream: don't pollute L2
    atomicAdd(&deg[r], 1);
  }
}

__device__ inline int wave_incl_scan(int v, int lane) {
#pragma unroll
  for (int off = 1; off < 64; off <<= 1) {
    int t = __shfl_up(v, off, 64);
    if (lane >= off) v += t;
  }
  return v;
}

// per-block (1024 elems) exclusive scan of deg -> rs; block totals -> bsums
__global__ __launch_bounds__(1024) void scan_phase1(const int* __restrict__ deg,
                                                    int* __restrict__ rs,
                                                    int* __restrict__ bsums) {
  int i = blockIdx.x * 1024 + threadIdx.x;
  int lane = threadIdx.x & 63, wave = threadIdx.x >> 6;   // wave 0..15
  int d = (i < NROWS) ? deg[i] : 0;
  int inc = wave_incl_scan(d, lane);
  __shared__ int wtot[16];
  if (lane == 63) wtot[wave] = inc;
  __syncthreads();
  int woff = 0;
  for (int wv = 0; wv < wave; ++wv) woff += wtot[wv];
  if (i < NROWS) rs[i] = woff + inc - d;
  if (threadIdx.x == 1023) bsums[blockIdx.x] = woff + inc;
}

// in-place exclusive scan of block sums (nb <= 1024), single block
__global__ __launch_bounds__(1024) void scan_phase2(int* __restrict__ bsums, int nb) {
  int t = threadIdx.x, lane = t & 63, wave = t >> 6;
  int d = (t < nb) ? bsums[t] : 0;
  int inc = wave_incl_scan(d, lane);
  __shared__ int wtot[16];
  if (lane == 63) wtot[wave] = inc;
  __syncthreads();
  int woff = 0;
  for (int wv = 0; wv < wave; ++wv) woff += wtot[wv];
  if (t < nb) bsums[t] = woff + inc - d;
}

// add block offsets; init row cursors; init bucket cursors; write sentinel
__global__ __launch_bounds__(256) void scan_phase3(int* __restrict__ rs,
                                                   const int* __restrict__ bsums,
                                                   int* __restrict__ cur,
                                                   int* __restrict__ bcur) {
  int i = blockIdx.x * 256 + threadIdx.x;
  if (i < NROWS) {
    int v = rs[i] + bsums[i >> 10];
    rs[i]  = v;
    cur[i] = v;
  }
  if (i == 0) rs[NROWS] = E;
  if (i < NB) bcur[i] = i << SHIFT;   // bucket b's binned region starts at b*8192
}

// ---- Pass A: assign final positions, group records by bucket via LDS ------
__global__ __launch_bounds__(256) void bin_scatter(const int* __restrict__ row,
                                                   const int* __restrict__ col,
                                                   const float* __restrict__ val,
                                                   int* cur, int* bcur,
                                                   int2* __restrict__ binned) {
  __shared__ int hist[NB];              // per-bucket count in this chunk
  __shared__ int hcur[NB];              // exclusive scan, then placement cursor
  __shared__ int gbase[NB];             // global base - local base
  __shared__ int wt[4];
  __shared__ int2 lrec[CHUNK];          // grouped records (32 KB)
  __shared__ unsigned short lb[CHUNK];  // bucket id per slot (8 KB)

  const int t  = threadIdx.x;
  const int e0 = blockIdx.x * CHUNK;
  const int n  = min(CHUNK, E - e0);

  for (int i = t; i < NB; i += 256) hist[i] = 0;
  __syncthreads();

  // phase 1: load edges (coalesced), claim final pack positions, histogram buckets
  int pos[16], pc[16], pv[16];
#pragma unroll
  for (int i = 0; i < 16; ++i) {
    int e = e0 + 256 * i + t;
    pos[i] = -1;
    if (e < E) {
      int r  = __builtin_nontemporal_load(row + e);
      pc[i]  = __builtin_nontemporal_load(col + e);
      pv[i]  = __float_as_int(__builtin_nontemporal_load(val + e));
      pos[i] = atomicAdd(&cur[r], 1);
      atomicAdd(&hist[pos[i] >> SHIFT], 1);
    }
  }
  __syncthreads();

  // phase 2: exclusive scan of hist -> hcur (256 threads, 2 elems each; 512 >= NB)
  {
    int a = (2 * t < NB)     ? hist[2 * t]     : 0;
    int b = (2 * t + 1 < NB) ? hist[2 * t + 1] : 0;
    int s = a + b;
    int lane = t & 63, wv = t >> 6;
    int inc = wave_incl_scan(s, lane);
    if (lane == 63) wt[wv] = inc;
    __syncthreads();
    int woff = 0;
    for (int w = 0; w < wv; ++w) woff += wt[w];
    int excl = woff + inc - s;
    if (2 * t < NB)     hcur[2 * t]     = excl;
    if (2 * t + 1 < NB) hcur[2 * t + 1] = excl + a;
  }
  __syncthreads();

  // phase 3: one global allocation per touched bucket (STRIDED: NB > blockDim)
  for (int i = t; i < NB; i += 256) {
    int cnt = hist[i];
    int gb  = cnt ? atomicAdd(&bcur[i], cnt) : 0;
    gbase[i] = gb - hcur[i];
  }
  __syncthreads();

  // phase 4: rank + place records grouped by bucket in LDS
#pragma unroll
  for (int i = 0; i < 16; ++i) {
    if (pos[i] >= 0) {
      int b = pos[i] >> SHIFT;
      int l = atomicAdd(&hcur[b], 1);
      lrec[l] = make_int2((pos[i] & ((1 << SHIFT) - 1)) | (pc[i] << SHIFT), pv[i]);
      lb[l]   = (unsigned short)b;
    }
  }
  __syncthreads();

  // phase 5: copy out — consecutive slots of a bucket hit consecutive global
  // addresses (avg run ~10 recs = 84B) -> mostly full-line writes
  for (int l = t; l < n; l += 256) {
    int b = lb[l];
    binned[gbase[b] + l] = lrec[l];
  }
}

// ---- Pass B: scatter within L2-resident 32KB pack windows -----------------
__global__ __launch_bounds__(256) void debin(const int2* __restrict__ binned,
                                             int2* __restrict__ pack) {
  int b     = blockIdx.x >> 1;
  int half  = blockIdx.x & 1;
  int start = (b << SHIFT) + half * 4096;
  int end   = min(E, start + 4096);
  for (int idx = start + threadIdx.x; idx < end; idx += 256) {
    int2 rec = binned[idx];
    int pos  = (b << SHIFT) | (rec.x & ((1 << SHIFT) - 1));
    pack[pos] = make_int2(((unsigned)rec.x) >> SHIFT, rec.y);
  }
}

// ---------------------------------------------------------------------------
// Pull-based SPMM: one wave per row, lane = column. No atomics.
// ---------------------------------------------------------------------------
__global__ __launch_bounds__(256) void spmm_pull(const int* __restrict__ rs,
                                                 const int2* __restrict__ pack,
                                                 const float* __restrict__ hin,
                                                 float* __restrict__ hout) {
  int r = blockIdx.x * 4 + (threadIdx.x >> 6);
  if (r >= NROWS) return;
  int lane  = threadIdx.x & 63;
  int start = rs[r], end = rs[r + 1];
  float acc = 0.f;
  for (int base = start; base < end; base += 64) {
    int idx = base + lane;
    int2 p  = (idx < end) ? pack[idx] : make_int2(0, 0);  // col 0 / val 0 pad is safe
    int n   = min(64, end - base);
    int nn  = (n + 3) & ~3;
    for (int j = 0; j < nn; j += 4) {
      // j is wave-uniform -> these lower to v_readlane broadcasts
      int   c0 = __shfl(p.x, j, 64),     c1 = __shfl(p.x, j + 1, 64);
      int   c2 = __shfl(p.x, j + 2, 64), c3 = __shfl(p.x, j + 3, 64);
      float v0 = __int_as_float(__shfl(p.y, j, 64));
      float v1 = __int_as_float(__shfl(p.y, j + 1, 64));
      float v2 = __int_as_float(__shfl(p.y, j + 2, 64));
      float v3 = __int_as_float(__shfl(p.y, j + 3, 64));
      float g0 = hin[(size_t)c0 * C + lane];
      float g1 = hin[(size_t)c1 * C + lane];
      float g2 = hin[(size_t)c2 * C + lane];
      float g3 = hin[(size_t)c3 * C + lane];
      acc += v0 * g0; acc += v1 * g1; acc += v2 * g2; acc += v3 * g3;
    }
  }
  hout[(size_t)r * C + lane] = acc;
}

// ---------------------------------------------------------------------------
// Fallback SPMM (atomic push) if ws too small for CSR
// ---------------------------------------------------------------------------
__global__ __launch_bounds__(256) void spmm_atomic(const int* __restrict__ row,
                                                   const int* __restrict__ col,
                                                   const float* __restrict__ val,
                                                   const float* __restrict__ hin,
                                                   float* hout) {
  int e = blockIdx.x * 4 + (threadIdx.x >> 6);
  if (e >= E) return;
  int   c  = threadIdx.x & 63;
  int   r  = row[e];
  int   cl = col[e];
  float v  = val[e];
  atomicAdd(&hout[(size_t)r * C + c], v * hin[(size_t)cl * C + c]);
}

// ---------------------------------------------------------------------------
// bias + log_softmax, one wave per row (C=64 = wave width)
// ---------------------------------------------------------------------------
__global__ __launch_bounds__(256) void bias_lsm(const float* __restrict__ h,
                                                const float* __restrict__ bias,
                                                float* __restrict__ out) {
  int r = blockIdx.x * 4 + (threadIdx.x >> 6);
  if (r >= NROWS) return;
  int   c = threadIdx.x & 63;
  float v = h[(size_t)r * C + c] + bias[c];

  float m = v;
#pragma unroll
  for (int off = 32; off; off >>= 1) m = fmaxf(m, __shfl_xor(m, off, 64));
  float ex = __expf(v - m);
  float s  = ex;
#pragma unroll
  for (int off = 32; off; off >>= 1) s += __shfl_xor(s, off, 64);

  out[(size_t)r * C + c] = v - m - __logf(s);
}

// ---------------------------------------------------------------------------
extern "C" void kernel_launch(void* const* d_in, const int* in_sizes, int n_in,
                              void* d_out, int out_size, void* d_ws, size_t ws_size,
                              hipStream_t stream) {
  const float* x    = (const float*)d_in[0];
  const float* w    = (const float*)d_in[1];
  const float* bias = (const float*)d_in[2];
  const int*   erow = (const int*)d_in[3];
  const int*   ecol = (const int*)d_in[4];
  const float* eval = (const float*)d_in[5];

  float* out = (float*)d_out;

  const size_t hbytes = (size_t)NROWS * C * sizeof(float);   // 25.6 MB
  const size_t pbytes = (size_t)E * 8;                       // 25.6 MB
  char* ws = (char*)d_ws;

  // Region A: binned (pass A/B) THEN h0 (gemm runs after debin) — aliased.
  const size_t regA = (pbytes > hbytes) ? pbytes : hbytes;

  const int nblk_edges = (E + 255) / 256;         // 12500
  const int nb1        = (NROWS + 1023) / 1024;   // 98 scan blocks
  const int nblk_binA  = (E + CHUNK - 1) / CHUNK; // 782

  size_t need = regA + pbytes + ((size_t)NROWS + 16) * 4 + (size_t)NROWS * 4
              + (size_t)NB * 4 + 8192;

  if (ws_size >= need) {
    char* p = ws;
    char* regA_p = p;                 p += regA;
    int2* pack   = (int2*)p;          p += pbytes;
    int*  rs     = (int*)p;           p += ((size_t)NROWS + 16) * 4;
    int*  cur    = (int*)p;           p += (size_t)NROWS * 4;       // also deg
    int*  bcur   = (int*)p;           p += (size_t)NB * 4;
    int*  bsums  = (int*)p;

    int2*  binned = (int2*)regA_p;
    float* h0     = (float*)regA_p;   // overwrites binned after debin
    float* hA     = out;              // d_out doubles as intermediate h buffer

    // ---- build CSR via binned counting scatter ----
    hipMemsetAsync(cur, 0, (size_t)NROWS * 4, stream);
    hist_kernel<<<nblk_edges, 256, 0, stream>>>(erow, cur);           // cur = deg
    scan_phase1<<<nb1, 1024, 0, stream>>>(cur, rs, bsums);
    scan_phase2<<<1, 1024, 0, stream>>>(bsums, nb1);
    scan_phase3<<<(NROWS + 255) / 256, 256, 0, stream>>>(rs, bsums, cur, bcur);
    bin_scatter<<<nblk_binA, 256, 0, stream>>>(erow, ecol, eval, cur, bcur, binned);
    debin<<<NB * 2, 256, 0, stream>>>(binned, pack);

    // ---- dense GEMM (h0 overwrites the dead binned region) ----
    gemm64<<<(NROWS + 127) / 128, 256, 0, stream>>>(x, w, h0);

    // ---- two propagation layers, pull-based ----
    spmm_pull<<<(NROWS + 3) / 4, 256, 0, stream>>>(rs, pack, h0, hA);
    spmm_pull<<<(NROWS + 3) / 4, 256, 0, stream>>>(rs, pack, hA, h0);

    // out = log_softmax(h0 + bias)
    bias_lsm<<<(NROWS + 3) / 4, 256, 0, stream>>>(h0, bias, out);
  } else {
    // fallback: atomic push (hA = d_out as scratch)
    float* h0 = (float*)ws;
    float* hA = out;
    gemm64<<<(NROWS + 127) / 128, 256, 0, stream>>>(x, w, h0);
    hipMemsetAsync(hA, 0, hbytes, stream);
    spmm_atomic<<<(E + 3) / 4, 256, 0, stream>>>(erow, ecol, eval, h0, hA);
    hipMemsetAsync(h0, 0, hbytes, stream);
    spmm_atomic<<<(E + 3) / 4, 256, 0, stream>>>(erow, ecol, eval, hA, h0);
    bias_lsm<<<(NROWS + 3) / 4, 256, 0, stream>>>(h0, bias, out);
  }
}